// Round 2
// baseline (1447.346 us; speedup 1.0000x reference)
//
#include <hip/hip_runtime.h>

#define WAVE 64

// ---------------- CSR build ----------------

__global__ void k_count(const int* __restrict__ dst, const int* __restrict__ typ,
                        int* __restrict__ cnt4, int E) {
    int e = blockIdx.x * 256 + threadIdx.x;
    if (e < E) atomicAdd(&cnt4[dst[e] * 4 + typ[e]], 1);
}

// exclusive scan over M=4N elems; 1024 elems/block
__global__ void k_scan1(const int* __restrict__ in, int* __restrict__ out,
                        int* __restrict__ bsum, int M) {
    __shared__ int s[256];
    int t = threadIdx.x;
    int base = blockIdx.x * 1024 + t * 4;
    int v0 = (base + 0 < M) ? in[base + 0] : 0;
    int v1 = (base + 1 < M) ? in[base + 1] : 0;
    int v2 = (base + 2 < M) ? in[base + 2] : 0;
    int v3 = (base + 3 < M) ? in[base + 3] : 0;
    int ts = v0 + v1 + v2 + v3;
    s[t] = ts;
    __syncthreads();
    for (int off = 1; off < 256; off <<= 1) {
        int x = (t >= off) ? s[t - off] : 0;
        __syncthreads();
        s[t] += x;
        __syncthreads();
    }
    int excl = (t == 0) ? 0 : s[t - 1];
    if (t == 255) bsum[blockIdx.x] = s[255];
    if (base + 0 < M) out[base + 0] = excl;
    if (base + 1 < M) out[base + 1] = excl + v0;
    if (base + 2 < M) out[base + 2] = excl + v0 + v1;
    if (base + 3 < M) out[base + 3] = excl + v0 + v1 + v2;
}

__global__ void k_scan2(const int* __restrict__ bsum, int* __restrict__ boff, int nb) {
    __shared__ int s[512];
    int t = threadIdx.x;
    s[t] = (t < nb) ? bsum[t] : 0;
    __syncthreads();
    for (int off = 1; off < 512; off <<= 1) {
        int x = (t >= off) ? s[t - off] : 0;
        __syncthreads();
        s[t] += x;
        __syncthreads();
    }
    if (t < nb) boff[t] = (t == 0) ? 0 : s[t - 1];
}

__global__ void k_scan3(int* __restrict__ out, const int* __restrict__ boff, int M, int E) {
    int i = blockIdx.x * 256 + threadIdx.x;
    if (i < M) out[i] += boff[i >> 10];
    else if (i == M) out[M] = E;
}

__global__ void k_fill(const int* __restrict__ src, const int* __restrict__ dst,
                       const int* __restrict__ typ, const int* __restrict__ start4,
                       int* __restrict__ cursor4, int* __restrict__ elist, int E) {
    int e = blockIdx.x * 256 + threadIdx.x;
    if (e < E) {
        int seg = dst[e] * 4 + typ[e];
        int p = atomicAdd(&cursor4[seg], 1);
        elist[start4[seg] + p] = src[e];
    }
}

// ---------------- weight concat: Wcat[l][k<320][h<64] = [W_r rows | root rows] ----------------

__global__ void k_wcat(const float* __restrict__ W1, const float* __restrict__ root1,
                       const float* __restrict__ Wl, const float* __restrict__ rootl,
                       float* __restrict__ Wcat) {
    int idx = blockIdx.x * 256 + threadIdx.x;
    const int TOT = 3 * 320 * 64;
    if (idx >= TOT) return;
    int l = idx / (320 * 64);
    int rem = idx - l * (320 * 64);
    int k = rem >> 6;
    int h = rem & 63;
    float v;
    if (k < 256) {
        v = (l == 0) ? W1[k * 64 + h] : Wl[(l - 1) * 16384 + k * 64 + h];
    } else {
        v = (l == 0) ? root1[(k - 256) * 64 + h] : rootl[(l - 1) * 4096 + (k - 256) * 64 + h];
    }
    Wcat[idx] = v;
}

// ---------------- fused RGCN conv layer ----------------
// A-tile LDS layout: elem (k, n) at k*64 + (n ^ ((k&7)<<2)). 16B-granular XOR swizzle:
// phase-1 column writes (lanes vary k) and phase-2 float4 row reads both ~2-way => free.
#define SWZ(k, n) ((k) * 64 + ((n) ^ (((k) & 7) << 2)))

#define AGGR(beg, end, outv)                                                         \
    {                                                                                \
        float acc = 0.f, accb = 0.f;                                                 \
        int p = (beg);                                                               \
        for (; p + 4 <= (end); p += 4) {                                             \
            int s0 = elist[p], s1 = elist[p + 1], s2 = elist[p + 2], s3 = elist[p + 3]; \
            acc  += hin[s0 * 64 + lane];                                             \
            accb += hin[s1 * 64 + lane];                                             \
            acc  += hin[s2 * 64 + lane];                                             \
            accb += hin[s3 * 64 + lane];                                             \
        }                                                                            \
        for (; p < (end); ++p) acc += hin[elist[p] * 64 + lane];                     \
        int c = (end) - (beg);                                                       \
        outv = (acc + accb) * ((c > 0) ? (1.0f / (float)c) : 0.0f);                  \
    }

__global__ __launch_bounds__(256, 2) void k_conv(
        const float* __restrict__ hin, float* __restrict__ hout,
        const int* __restrict__ elist, const int* __restrict__ start4,
        const float* __restrict__ Wc, const float* __restrict__ bias, int nN) {
    extern __shared__ float A[];  // 320*64 floats = 80 KB
    const int tid = threadIdx.x;
    const int lane = tid & 63;
    const int wv = tid >> 6;
    const int tile = blockIdx.x * 64;

    // phase 1: aggregate 16 nodes per wave into LDS A-tile
    for (int jj = 0; jj < 16; ++jj) {
        int nl = wv * 16 + jj;
        int n = tile + nl;
        if (n < nN) {
            const int* s4 = start4 + n * 4;
            int e0 = s4[0], e1 = s4[1], e2 = s4[2], e3 = s4[3], e4 = s4[4];
            float self = hin[n * 64 + lane];
            float a0, a1, a2, a3;
            AGGR(e0, e1, a0);
            AGGR(e1, e2, a1);
            AGGR(e2, e3, a2);
            AGGR(e3, e4, a3);
            A[SWZ(0 + lane, nl)]   = a0;
            A[SWZ(64 + lane, nl)]  = a1;
            A[SWZ(128 + lane, nl)] = a2;
            A[SWZ(192 + lane, nl)] = a3;
            A[SWZ(256 + lane, nl)] = self;
        }
    }
    __syncthreads();

    // phase 2: C[64n x 64h] = A[320 x 64n]^T * Wc[320 x 64h]; 4x4 per thread
    const int n0 = (tid & 15) << 2;
    const int h0 = (tid >> 4) << 2;
    float cc[4][4];
#pragma unroll
    for (int i = 0; i < 4; ++i)
#pragma unroll
        for (int j = 0; j < 4; ++j) cc[i][j] = 0.f;

#pragma unroll 8
    for (int k = 0; k < 320; ++k) {
        const float4 a = *reinterpret_cast<const float4*>(&A[k * 64 + (n0 ^ ((k & 7) << 2))]);
        const float4 w = *reinterpret_cast<const float4*>(&Wc[k * 64 + h0]);
        cc[0][0] += a.x * w.x; cc[0][1] += a.x * w.y; cc[0][2] += a.x * w.z; cc[0][3] += a.x * w.w;
        cc[1][0] += a.y * w.x; cc[1][1] += a.y * w.y; cc[1][2] += a.y * w.z; cc[1][3] += a.y * w.w;
        cc[2][0] += a.z * w.x; cc[2][1] += a.z * w.y; cc[2][2] += a.z * w.z; cc[2][3] += a.z * w.w;
        cc[3][0] += a.w * w.x; cc[3][1] += a.w * w.y; cc[3][2] += a.w * w.z; cc[3][3] += a.w * w.w;
    }

    const float b0 = bias[h0 + 0], b1 = bias[h0 + 1], b2 = bias[h0 + 2], b3 = bias[h0 + 3];
#pragma unroll
    for (int i = 0; i < 4; ++i) {
        int n = tile + n0 + i;
        if (n < nN) {
            float4 o;
            o.x = fmaxf(cc[i][0] + b0, 0.f);
            o.y = fmaxf(cc[i][1] + b1, 0.f);
            o.z = fmaxf(cc[i][2] + b2, 0.f);
            o.w = fmaxf(cc[i][3] + b3, 0.f);
            *reinterpret_cast<float4*>(&hout[n * 64 + h0]) = o;
        }
    }
}

// ---------------- pooling ----------------

__global__ void k_pool(const float* __restrict__ h, const int* __restrict__ batch,
                       float* __restrict__ g_sum, int nN) {
    int gid = blockIdx.x * 256 + threadIdx.x;
    int hi = gid & 63;
    int n0 = (gid >> 6) * 8;
    if (n0 >= nN) return;
    int end = n0 + 8;
    if (end > nN) end = nN;
    float acc = 0.f;
    int cur = batch[n0];
    for (int n = n0; n < end; ++n) {
        int b = batch[n];
        if (b != cur) {
            atomicAdd(&g_sum[cur * 64 + hi], acc);
            acc = 0.f;
            cur = b;
        }
        acc += h[n * 64 + hi];
    }
    atomicAdd(&g_sum[cur * 64 + hi], acc);
}

__global__ void k_cntg(const int* __restrict__ batch, float* __restrict__ cnt_g, int nN) {
    int n = blockIdx.x * 256 + threadIdx.x;
    if (n < nN) atomicAdd(&cnt_g[batch[n]], 1.0f);
}

// ---------------- final MLP: g -> relu(g@w1+b1) -> @w2+b2 ----------------

__global__ void k_mlp(const float* __restrict__ g_sum, const float* __restrict__ cnt_g,
                      const float* __restrict__ w1, const float* __restrict__ b1,
                      const float* __restrict__ w2, const float* __restrict__ b2,
                      float* __restrict__ out) {
    __shared__ float sg[64];
    __shared__ float sh[64];
    int g = blockIdx.x;
    int h = threadIdx.x;
    float c = cnt_g[g];
    sg[h] = g_sum[g * 64 + h] / fmaxf(c, 1.0f);
    __syncthreads();
    float acc = b1[h];
#pragma unroll
    for (int f = 0; f < 64; ++f) acc += sg[f] * w1[f * 64 + h];
    sh[h] = fmaxf(acc, 0.f);
    __syncthreads();
    if (h < 10) {
        float o = b2[h];
#pragma unroll
        for (int f = 0; f < 64; ++f) o += sh[f] * w2[f * 10 + h];
        out[g * 10 + h] = o;
    }
}

// ---------------- launch ----------------

extern "C" void kernel_launch(void* const* d_in, const int* in_sizes, int n_in,
                              void* d_out, int out_size, void* d_ws, size_t ws_size,
                              hipStream_t stream) {
    const float* x     = (const float*)d_in[0];
    const int*   ei    = (const int*)d_in[1];
    const int*   et    = (const int*)d_in[2];
    const int*   batch = (const int*)d_in[3];
    const float* W1    = (const float*)d_in[4];
    const float* root1 = (const float*)d_in[5];
    const float* b1    = (const float*)d_in[6];
    const float* Wl    = (const float*)d_in[7];
    const float* rootl = (const float*)d_in[8];
    const float* bl    = (const float*)d_in[9];
    const float* l1w   = (const float*)d_in[10];
    const float* l1b   = (const float*)d_in[11];
    const float* l2w   = (const float*)d_in[12];
    const float* l2b   = (const float*)d_in[13];
    float* out = (float*)d_out;

    const int N = in_sizes[3];
    const int E = in_sizes[2];
    const int G = out_size / 10;
    const int M = 4 * N;

    const int* src = ei;
    const int* dst = ei + E;

    // workspace carve-out (512B aligned)
    char* base = (char*)d_ws;
    size_t off = 0;
    auto carve = [&](size_t bytes) {
        char* p = base + off;
        off = (off + bytes + 511) & ~(size_t)511;
        return p;
    };
    int*   cnt4    = (int*)carve((size_t)M * 4);
    int*   start4  = (int*)carve((size_t)(M + 1) * 4);
    int*   cursor4 = (int*)carve((size_t)M * 4);
    int*   elist   = (int*)carve((size_t)E * 4);
    int*   bsum    = (int*)carve(512 * 4);
    int*   boff    = (int*)carve(512 * 4);
    float* Wcat    = (float*)carve((size_t)3 * 320 * 64 * 4);
    float* h_a     = (float*)carve((size_t)N * 64 * 4);
    float* h_b     = (float*)carve((size_t)N * 64 * 4);
    float* g_sum   = (float*)carve((size_t)G * 64 * 4);
    float* cnt_g   = (float*)carve((size_t)G * 4);
    (void)ws_size;

    hipMemsetAsync(cnt4, 0, (size_t)M * 4, stream);
    hipMemsetAsync(cursor4, 0, (size_t)M * 4, stream);
    hipMemsetAsync(g_sum, 0, (size_t)G * 64 * 4, stream);
    hipMemsetAsync(cnt_g, 0, (size_t)G * 4, stream);

    k_count<<<(E + 255) / 256, 256, 0, stream>>>(dst, et, cnt4, E);

    int nb = (M + 1023) / 1024;
    k_scan1<<<nb, 256, 0, stream>>>(cnt4, start4, bsum, M);
    k_scan2<<<1, 512, 0, stream>>>(bsum, boff, nb);
    k_scan3<<<(M + 1 + 255) / 256, 256, 0, stream>>>(start4, boff, M, E);
    k_fill<<<(E + 255) / 256, 256, 0, stream>>>(src, dst, et, start4, cursor4, elist, E);

    k_wcat<<<(3 * 320 * 64 + 255) / 256, 256, 0, stream>>>(W1, root1, Wl, rootl, Wcat);

    static bool attr_set = false;
    if (!attr_set) {
        hipFuncSetAttribute((const void*)k_conv,
                            hipFuncAttributeMaxDynamicSharedMemorySize, 320 * 64 * 4);
        attr_set = true;
    }

    const int cb = (N + 63) / 64;
    const size_t lds = 320 * 64 * 4;
    k_conv<<<cb, 256, lds, stream>>>(x,   h_a, elist, start4, Wcat,                b1,      N);
    k_conv<<<cb, 256, lds, stream>>>(h_a, h_b, elist, start4, Wcat + 320 * 64,     bl,      N);
    k_conv<<<cb, 256, lds, stream>>>(h_b, h_a, elist, start4, Wcat + 2 * 320 * 64, bl + 64, N);

    k_pool<<<(((N + 7) / 8) * 64 + 255) / 256, 256, 0, stream>>>(h_a, batch, g_sum, N);
    k_cntg<<<(N + 255) / 256, 256, 0, stream>>>(batch, cnt_g, N);
    k_mlp<<<G, 64, 0, stream>>>(g_sum, cnt_g, l1w, l1b, l2w, l2b, out);
}

// Round 3
// 1020.278 us; speedup vs baseline: 1.4186x; 1.4186x over previous
//
#include <hip/hip_runtime.h>

#define WAVE 64

// ---------------- CSR build ----------------

__global__ void k_count(const int* __restrict__ dst, const int* __restrict__ typ,
                        int* __restrict__ cnt4, int E) {
    int e = blockIdx.x * 256 + threadIdx.x;
    if (e < E) atomicAdd(&cnt4[dst[e] * 4 + typ[e]], 1);
}

// exclusive scan over M=4N elems; 1024 elems/block
__global__ void k_scan1(const int* __restrict__ in, int* __restrict__ out,
                        int* __restrict__ bsum, int M) {
    __shared__ int s[256];
    int t = threadIdx.x;
    int base = blockIdx.x * 1024 + t * 4;
    int v0 = (base + 0 < M) ? in[base + 0] : 0;
    int v1 = (base + 1 < M) ? in[base + 1] : 0;
    int v2 = (base + 2 < M) ? in[base + 2] : 0;
    int v3 = (base + 3 < M) ? in[base + 3] : 0;
    int ts = v0 + v1 + v2 + v3;
    s[t] = ts;
    __syncthreads();
    for (int off = 1; off < 256; off <<= 1) {
        int x = (t >= off) ? s[t - off] : 0;
        __syncthreads();
        s[t] += x;
        __syncthreads();
    }
    int excl = (t == 0) ? 0 : s[t - 1];
    if (t == 255) bsum[blockIdx.x] = s[255];
    if (base + 0 < M) out[base + 0] = excl;
    if (base + 1 < M) out[base + 1] = excl + v0;
    if (base + 2 < M) out[base + 2] = excl + v0 + v1;
    if (base + 3 < M) out[base + 3] = excl + v0 + v1 + v2;
}

__global__ void k_scan2(const int* __restrict__ bsum, int* __restrict__ boff, int nb) {
    __shared__ int s[512];
    int t = threadIdx.x;
    s[t] = (t < nb) ? bsum[t] : 0;
    __syncthreads();
    for (int off = 1; off < 512; off <<= 1) {
        int x = (t >= off) ? s[t - off] : 0;
        __syncthreads();
        s[t] += x;
        __syncthreads();
    }
    if (t < nb) boff[t] = (t == 0) ? 0 : s[t - 1];
}

__global__ void k_scan3(int* __restrict__ out, const int* __restrict__ boff, int M, int E) {
    int i = blockIdx.x * 256 + threadIdx.x;
    if (i < M) out[i] += boff[i >> 10];
    else if (i == M) out[M] = E;
}

__global__ void k_fill(const int* __restrict__ src, const int* __restrict__ dst,
                       const int* __restrict__ typ, const int* __restrict__ start4,
                       int* __restrict__ cursor4, int* __restrict__ elist, int E) {
    int e = blockIdx.x * 256 + threadIdx.x;
    if (e < E) {
        int seg = dst[e] * 4 + typ[e];
        int p = atomicAdd(&cursor4[seg], 1);
        elist[start4[seg] + p] = src[e];
    }
}

// ---------------- weight concat: Wcat[l][k<320][h<64] = [W_r rows | root rows] ----------------

__global__ void k_wcat(const float* __restrict__ W1, const float* __restrict__ root1,
                       const float* __restrict__ Wl, const float* __restrict__ rootl,
                       float* __restrict__ Wcat) {
    int idx = blockIdx.x * 256 + threadIdx.x;
    const int TOT = 3 * 320 * 64;
    if (idx >= TOT) return;
    int l = idx / (320 * 64);
    int rem = idx - l * (320 * 64);
    int k = rem >> 6;
    int h = rem & 63;
    float v;
    if (k < 256) {
        v = (l == 0) ? W1[k * 64 + h] : Wl[(l - 1) * 16384 + k * 64 + h];
    } else {
        v = (l == 0) ? root1[(k - 256) * 64 + h] : rootl[(l - 1) * 4096 + (k - 256) * 64 + h];
    }
    Wcat[idx] = v;
}

// ---------------- fused RGCN conv layer ----------------
// A-tile LDS layout: elem (k, n) at k*64 + (n ^ ((k&7)<<2)). 16B-granular XOR swizzle:
// phase-1 column writes (lanes vary k) and phase-2 float4 row reads both ~2-way => free.
#define SWZ(k, n) ((k) * 64 + ((n) ^ (((k) & 7) << 2)))

__global__ __launch_bounds__(256, 2) void k_conv(
        const float* __restrict__ hin, float* __restrict__ hout,
        const int* __restrict__ elist, const int* __restrict__ start4,
        const float* __restrict__ Wc, const float* __restrict__ bias, int nN) {
    extern __shared__ float A[];  // 320*64 floats = 80 KB
    const int tid = threadIdx.x;
    const int lane = tid & 63;
    const int wv = tid >> 6;
    const int tile = blockIdx.x * 64;

    // phase 1: aggregate 16 nodes per wave into LDS A-tile.
    // Flat edge loop per node, unroll x8: 8 independent (elist -> hin-row) chains
    // in flight per wave; relation routing via branchless predicated accumulate.
    for (int jj = 0; jj < 16; ++jj) {
        int nl = wv * 16 + jj;
        int n = tile + nl;
        if (n >= nN) break;
        const int* s4 = start4 + n * 4;
        int e0 = s4[0], e1 = s4[1], e2 = s4[2], e3 = s4[3], e4 = s4[4];
        float self = hin[(size_t)n * 64 + lane];
        float a0 = 0.f, a1 = 0.f, a2 = 0.f, a3 = 0.f;
        for (int p = e0; p < e4; p += 8) {
            int qidx[8];
#pragma unroll
            for (int u = 0; u < 8; ++u) {
                int q = p + u;
                qidx[u] = elist[(q < e4) ? q : e0];
            }
            float v[8];
#pragma unroll
            for (int u = 0; u < 8; ++u)
                v[u] = hin[(size_t)qidx[u] * 64 + lane];
#pragma unroll
            for (int u = 0; u < 8; ++u) {
                int q = p + u;
                a0 += (q < e1) ? v[u] : 0.f;
                a1 += (q >= e1 && q < e2) ? v[u] : 0.f;
                a2 += (q >= e2 && q < e3) ? v[u] : 0.f;
                a3 += (q >= e3 && q < e4) ? v[u] : 0.f;
            }
        }
        int c0 = e1 - e0, c1 = e2 - e1, c2 = e3 - e2, c3 = e4 - e3;
        a0 *= (c0 > 0) ? 1.0f / (float)c0 : 0.f;
        a1 *= (c1 > 0) ? 1.0f / (float)c1 : 0.f;
        a2 *= (c2 > 0) ? 1.0f / (float)c2 : 0.f;
        a3 *= (c3 > 0) ? 1.0f / (float)c3 : 0.f;
        A[SWZ(0 + lane, nl)]   = a0;
        A[SWZ(64 + lane, nl)]  = a1;
        A[SWZ(128 + lane, nl)] = a2;
        A[SWZ(192 + lane, nl)] = a3;
        A[SWZ(256 + lane, nl)] = self;
    }
    __syncthreads();

    // phase 2: C[64n x 64h] = A[320 x 64n]^T * Wc[320 x 64h]; 4x4 per thread
    const int n0 = (tid & 15) << 2;
    const int h0 = (tid >> 4) << 2;
    float cc[4][4];
#pragma unroll
    for (int i = 0; i < 4; ++i)
#pragma unroll
        for (int j = 0; j < 4; ++j) cc[i][j] = 0.f;

#pragma unroll 8
    for (int k = 0; k < 320; ++k) {
        const float4 a = *reinterpret_cast<const float4*>(&A[k * 64 + (n0 ^ ((k & 7) << 2))]);
        const float4 w = *reinterpret_cast<const float4*>(&Wc[k * 64 + h0]);
        cc[0][0] += a.x * w.x; cc[0][1] += a.x * w.y; cc[0][2] += a.x * w.z; cc[0][3] += a.x * w.w;
        cc[1][0] += a.y * w.x; cc[1][1] += a.y * w.y; cc[1][2] += a.y * w.z; cc[1][3] += a.y * w.w;
        cc[2][0] += a.z * w.x; cc[2][1] += a.z * w.y; cc[2][2] += a.z * w.z; cc[2][3] += a.z * w.w;
        cc[3][0] += a.w * w.x; cc[3][1] += a.w * w.y; cc[3][2] += a.w * w.z; cc[3][3] += a.w * w.w;
    }

    const float b0 = bias[h0 + 0], b1 = bias[h0 + 1], b2 = bias[h0 + 2], b3 = bias[h0 + 3];
#pragma unroll
    for (int i = 0; i < 4; ++i) {
        int n = tile + n0 + i;
        if (n < nN) {
            float4 o;
            o.x = fmaxf(cc[i][0] + b0, 0.f);
            o.y = fmaxf(cc[i][1] + b1, 0.f);
            o.z = fmaxf(cc[i][2] + b2, 0.f);
            o.w = fmaxf(cc[i][3] + b3, 0.f);
            *reinterpret_cast<float4*>(&hout[n * 64 + h0]) = o;
        }
    }
}

// ---------------- pooling ----------------

__global__ void k_pool(const float* __restrict__ h, const int* __restrict__ batch,
                       float* __restrict__ g_sum, int nN) {
    int gid = blockIdx.x * 256 + threadIdx.x;
    int hi = gid & 63;
    int n0 = (gid >> 6) * 8;
    if (n0 >= nN) return;
    int end = n0 + 8;
    if (end > nN) end = nN;
    float acc = 0.f;
    int cur = batch[n0];
    for (int n = n0; n < end; ++n) {
        int b = batch[n];
        if (b != cur) {
            atomicAdd(&g_sum[cur * 64 + hi], acc);
            acc = 0.f;
            cur = b;
        }
        acc += h[n * 64 + hi];
    }
    atomicAdd(&g_sum[cur * 64 + hi], acc);
}

__global__ void k_cntg(const int* __restrict__ batch, float* __restrict__ cnt_g, int nN) {
    int n = blockIdx.x * 256 + threadIdx.x;
    if (n < nN) atomicAdd(&cnt_g[batch[n]], 1.0f);
}

// ---------------- final MLP: g -> relu(g@w1+b1) -> @w2+b2 ----------------

__global__ void k_mlp(const float* __restrict__ g_sum, const float* __restrict__ cnt_g,
                      const float* __restrict__ w1, const float* __restrict__ b1,
                      const float* __restrict__ w2, const float* __restrict__ b2,
                      float* __restrict__ out) {
    __shared__ float sg[64];
    __shared__ float sh[64];
    int g = blockIdx.x;
    int h = threadIdx.x;
    float c = cnt_g[g];
    sg[h] = g_sum[g * 64 + h] / fmaxf(c, 1.0f);
    __syncthreads();
    float acc = b1[h];
#pragma unroll
    for (int f = 0; f < 64; ++f) acc += sg[f] * w1[f * 64 + h];
    sh[h] = fmaxf(acc, 0.f);
    __syncthreads();
    if (h < 10) {
        float o = b2[h];
#pragma unroll
        for (int f = 0; f < 64; ++f) o += sh[f] * w2[f * 10 + h];
        out[g * 10 + h] = o;
    }
}

// ---------------- launch ----------------

extern "C" void kernel_launch(void* const* d_in, const int* in_sizes, int n_in,
                              void* d_out, int out_size, void* d_ws, size_t ws_size,
                              hipStream_t stream) {
    const float* x     = (const float*)d_in[0];
    const int*   ei    = (const int*)d_in[1];
    const int*   et    = (const int*)d_in[2];
    const int*   batch = (const int*)d_in[3];
    const float* W1    = (const float*)d_in[4];
    const float* root1 = (const float*)d_in[5];
    const float* b1    = (const float*)d_in[6];
    const float* Wl    = (const float*)d_in[7];
    const float* rootl = (const float*)d_in[8];
    const float* bl    = (const float*)d_in[9];
    const float* l1w   = (const float*)d_in[10];
    const float* l1b   = (const float*)d_in[11];
    const float* l2w   = (const float*)d_in[12];
    const float* l2b   = (const float*)d_in[13];
    float* out = (float*)d_out;

    const int N = in_sizes[3];
    const int E = in_sizes[2];
    const int G = out_size / 10;
    const int M = 4 * N;

    const int* src = ei;
    const int* dst = ei + E;

    // workspace carve-out (512B aligned)
    char* base = (char*)d_ws;
    size_t off = 0;
    auto carve = [&](size_t bytes) {
        char* p = base + off;
        off = (off + bytes + 511) & ~(size_t)511;
        return p;
    };
    int*   cnt4    = (int*)carve((size_t)M * 4);
    int*   start4  = (int*)carve((size_t)(M + 1) * 4);
    int*   cursor4 = (int*)carve((size_t)M * 4);
    int*   elist   = (int*)carve((size_t)E * 4);
    int*   bsum    = (int*)carve(512 * 4);
    int*   boff    = (int*)carve(512 * 4);
    float* Wcat    = (float*)carve((size_t)3 * 320 * 64 * 4);
    float* h_a     = (float*)carve((size_t)N * 64 * 4);
    float* h_b     = (float*)carve((size_t)N * 64 * 4);
    float* g_sum   = (float*)carve((size_t)G * 64 * 4);
    float* cnt_g   = (float*)carve((size_t)G * 4);
    (void)ws_size;

    hipMemsetAsync(cnt4, 0, (size_t)M * 4, stream);
    hipMemsetAsync(cursor4, 0, (size_t)M * 4, stream);
    hipMemsetAsync(g_sum, 0, (size_t)G * 64 * 4, stream);
    hipMemsetAsync(cnt_g, 0, (size_t)G * 4, stream);

    k_count<<<(E + 255) / 256, 256, 0, stream>>>(dst, et, cnt4, E);

    int nb = (M + 1023) / 1024;
    k_scan1<<<nb, 256, 0, stream>>>(cnt4, start4, bsum, M);
    k_scan2<<<1, 512, 0, stream>>>(bsum, boff, nb);
    k_scan3<<<(M + 1 + 255) / 256, 256, 0, stream>>>(start4, boff, M, E);
    k_fill<<<(E + 255) / 256, 256, 0, stream>>>(src, dst, et, start4, cursor4, elist, E);

    k_wcat<<<(3 * 320 * 64 + 255) / 256, 256, 0, stream>>>(W1, root1, Wl, rootl, Wcat);

    static bool attr_set = false;
    if (!attr_set) {
        hipFuncSetAttribute((const void*)k_conv,
                            hipFuncAttributeMaxDynamicSharedMemorySize, 320 * 64 * 4);
        attr_set = true;
    }

    const int cb = (N + 63) / 64;
    const size_t lds = 320 * 64 * 4;
    k_conv<<<cb, 256, lds, stream>>>(x,   h_a, elist, start4, Wcat,                b1,      N);
    k_conv<<<cb, 256, lds, stream>>>(h_a, h_b, elist, start4, Wcat + 320 * 64,     bl,      N);
    k_conv<<<cb, 256, lds, stream>>>(h_b, h_a, elist, start4, Wcat + 2 * 320 * 64, bl + 64, N);

    k_pool<<<(((N + 7) / 8) * 64 + 255) / 256, 256, 0, stream>>>(h_a, batch, g_sum, N);
    k_cntg<<<(N + 255) / 256, 256, 0, stream>>>(batch, cnt_g, N);
    k_mlp<<<G, 64, 0, stream>>>(g_sum, cnt_g, l1w, l1b, l2w, l2b, out);
}